// Round 5
// baseline (105.960 us; speedup 1.0000x reference)
//
#include <hip/hip_runtime.h>

// out[i,j] = (z[i,:] . w) * w[j] + bias[j], all f32.  S=65536, B=1024.
// Persistent pipelined kernel: each block owns 2 rows.
//   Phase A: dot(z[r0], w)                         (pure read)
//   Phase B: NT-store out[r0] interleaved with dot(z[r1], w)  (read+write blended)
//   Phase C: NT-store out[r1]                      (pure write)
// Blended phase keeps the HBM bus fed with both streams; NT stores keep `out`
// from evicting z in the 256 MB Infinity Cache across graph replays.

#define SDIM 65536
#define S4   (SDIM / 4)   // 16384 float4 per row
#define BLK  512

typedef float floatx4 __attribute__((ext_vector_type(4)));

__device__ __forceinline__ float block_reduce(float acc, float* smem,
                                              volatile float* bcast)
{
    #pragma unroll
    for (int off = 32; off > 0; off >>= 1)
        acc += __shfl_down(acc, off, 64);
    const int lane = threadIdx.x & 63;
    const int wid  = threadIdx.x >> 6;
    if (lane == 0) smem[wid] = acc;
    __syncthreads();
    if (threadIdx.x == 0) {
        float t = 0.f;
        #pragma unroll
        for (int i = 0; i < BLK / 64; ++i) t += smem[i];
        *bcast = t;
    }
    __syncthreads();
    return *bcast;
}

__global__ __launch_bounds__(BLK) void fused_pipe_kernel(
    const float* __restrict__ z,
    const float* __restrict__ w,
    const float* __restrict__ bias,
    float* __restrict__ out)
{
    const int r0 = blockIdx.x * 2;
    const int r1 = r0 + 1;

    const floatx4* __restrict__ z0 =
        reinterpret_cast<const floatx4*>(z + (size_t)r0 * SDIM);
    const floatx4* __restrict__ z1 =
        reinterpret_cast<const floatx4*>(z + (size_t)r1 * SDIM);
    const floatx4* __restrict__ w4 = reinterpret_cast<const floatx4*>(w);
    const floatx4* __restrict__ b4 = reinterpret_cast<const floatx4*>(bias);
    floatx4* __restrict__ o0 =
        reinterpret_cast<floatx4*>(out + (size_t)r0 * SDIM);
    floatx4* __restrict__ o1 =
        reinterpret_cast<floatx4*>(out + (size_t)r1 * SDIM);

    __shared__ float smem[BLK / 64];
    __shared__ float bc0, bc1;

    // ---- Phase A: dot(z[r0], w) ----
    {
        float a0 = 0.f, a1 = 0.f, a2 = 0.f, a3 = 0.f;
        for (int i = threadIdx.x; i < S4; i += 4 * BLK) {
            floatx4 x0 = z0[i];
            floatx4 x1 = z0[i + BLK];
            floatx4 x2 = z0[i + 2 * BLK];
            floatx4 x3 = z0[i + 3 * BLK];
            floatx4 y0 = w4[i];
            floatx4 y1 = w4[i + BLK];
            floatx4 y2 = w4[i + 2 * BLK];
            floatx4 y3 = w4[i + 3 * BLK];
            a0 += x0.x * y0.x + x0.y * y0.y + x0.z * y0.z + x0.w * y0.w;
            a1 += x1.x * y1.x + x1.y * y1.y + x1.z * y1.z + x1.w * y1.w;
            a2 += x2.x * y2.x + x2.y * y2.y + x2.z * y2.z + x2.w * y2.w;
            a3 += x3.x * y3.x + x3.y * y3.y + x3.z * y3.z + x3.w * y3.w;
        }
        float acc = (a0 + a1) + (a2 + a3);
        float s0 = block_reduce(acc, smem, &bc0);
        bc0 = s0;  // keep value (no-op, silences unused-path elimination)
    }
    const float s0 = bc0;

    // ---- Phase B: write out[r0] (NT) while reading z[r1] for its dot ----
    {
        float a0 = 0.f, a1 = 0.f, a2 = 0.f, a3 = 0.f;
        for (int i = threadIdx.x; i < S4; i += 4 * BLK) {
            floatx4 x0 = z1[i];
            floatx4 x1 = z1[i + BLK];
            floatx4 x2 = z1[i + 2 * BLK];
            floatx4 x3 = z1[i + 3 * BLK];
            floatx4 y0 = w4[i];
            floatx4 y1 = w4[i + BLK];
            floatx4 y2 = w4[i + 2 * BLK];
            floatx4 y3 = w4[i + 3 * BLK];
            floatx4 c0 = b4[i];
            floatx4 c1 = b4[i + BLK];
            floatx4 c2 = b4[i + 2 * BLK];
            floatx4 c3 = b4[i + 3 * BLK];
            floatx4 r0v, r1v, r2v, r3v;
            r0v.x = fmaf(s0, y0.x, c0.x); r0v.y = fmaf(s0, y0.y, c0.y);
            r0v.z = fmaf(s0, y0.z, c0.z); r0v.w = fmaf(s0, y0.w, c0.w);
            r1v.x = fmaf(s0, y1.x, c1.x); r1v.y = fmaf(s0, y1.y, c1.y);
            r1v.z = fmaf(s0, y1.z, c1.z); r1v.w = fmaf(s0, y1.w, c1.w);
            r2v.x = fmaf(s0, y2.x, c2.x); r2v.y = fmaf(s0, y2.y, c2.y);
            r2v.z = fmaf(s0, y2.z, c2.z); r2v.w = fmaf(s0, y2.w, c2.w);
            r3v.x = fmaf(s0, y3.x, c3.x); r3v.y = fmaf(s0, y3.y, c3.y);
            r3v.z = fmaf(s0, y3.z, c3.z); r3v.w = fmaf(s0, y3.w, c3.w);
            __builtin_nontemporal_store(r0v, &o0[i]);
            __builtin_nontemporal_store(r1v, &o0[i + BLK]);
            __builtin_nontemporal_store(r2v, &o0[i + 2 * BLK]);
            __builtin_nontemporal_store(r3v, &o0[i + 3 * BLK]);
            a0 += x0.x * y0.x + x0.y * y0.y + x0.z * y0.z + x0.w * y0.w;
            a1 += x1.x * y1.x + x1.y * y1.y + x1.z * y1.z + x1.w * y1.w;
            a2 += x2.x * y2.x + x2.y * y2.y + x2.z * y2.z + x2.w * y2.w;
            a3 += x3.x * y3.x + x3.y * y3.y + x3.z * y3.z + x3.w * y3.w;
        }
        float acc = (a0 + a1) + (a2 + a3);
        float s1 = block_reduce(acc, smem, &bc1);
        bc1 = s1;
    }
    const float s1 = bc1;

    // ---- Phase C: write out[r1] (NT) ----
    for (int i = threadIdx.x; i < S4; i += 4 * BLK) {
        floatx4 y0 = w4[i];
        floatx4 y1 = w4[i + BLK];
        floatx4 y2 = w4[i + 2 * BLK];
        floatx4 y3 = w4[i + 3 * BLK];
        floatx4 c0 = b4[i];
        floatx4 c1 = b4[i + BLK];
        floatx4 c2 = b4[i + 2 * BLK];
        floatx4 c3 = b4[i + 3 * BLK];
        floatx4 r0v, r1v, r2v, r3v;
        r0v.x = fmaf(s1, y0.x, c0.x); r0v.y = fmaf(s1, y0.y, c0.y);
        r0v.z = fmaf(s1, y0.z, c0.z); r0v.w = fmaf(s1, y0.w, c0.w);
        r1v.x = fmaf(s1, y1.x, c1.x); r1v.y = fmaf(s1, y1.y, c1.y);
        r1v.z = fmaf(s1, y1.z, c1.z); r1v.w = fmaf(s1, y1.w, c1.w);
        r2v.x = fmaf(s1, y2.x, c2.x); r2v.y = fmaf(s1, y2.y, c2.y);
        r2v.z = fmaf(s1, y2.z, c2.z); r2v.w = fmaf(s1, y2.w, c2.w);
        r3v.x = fmaf(s1, y3.x, c3.x); r3v.y = fmaf(s1, y3.y, c3.y);
        r3v.z = fmaf(s1, y3.z, c3.z); r3v.w = fmaf(s1, y3.w, c3.w);
        __builtin_nontemporal_store(r0v, &o1[i]);
        __builtin_nontemporal_store(r1v, &o1[i + BLK]);
        __builtin_nontemporal_store(r2v, &o1[i + 2 * BLK]);
        __builtin_nontemporal_store(r3v, &o1[i + 3 * BLK]);
    }
}

extern "C" void kernel_launch(void* const* d_in, const int* in_sizes, int n_in,
                              void* d_out, int out_size, void* d_ws, size_t ws_size,
                              hipStream_t stream)
{
    const float* z    = (const float*)d_in[0];
    const float* w    = (const float*)d_in[1];  // (1,S,1) flat == (S,)
    const float* bias = (const float*)d_in[2];
    float* out = (float*)d_out;

    const int B = in_sizes[0] / SDIM;           // 1024

    fused_pipe_kernel<<<B / 2, BLK, 0, stream>>>(z, w, bias, out);
}